// Round 8
// baseline (8423.330 us; speedup 1.0000x reference)
//
#include <hip/hip_runtime.h>

// SNN-MNIST forward + STDP, MI355X persistent cooperative kernel.
// Round 12: panel-resident W. Block (bi,bn) keeps its W[64i][32n] panel in
// LDS for the whole run: STDP RMW is LDS-local, and after each update the
// block scatters sparse partial currents curp[bi][b][n] (ascending-i within
// panel) for the NEXT step. Phase 1 = 13 sc1 loads + register state
// (syn/mem/post in VGPRs). Pre-trace panel lives in tr_lds (inline update
// by the owning wave, R10-verified body). Active lists deleted.

#define T_STEPS 200
#define BATCH   256
#define INQ     784
#define NOUT    400
#define GRID    256
#define NTHR    512
#define IMSZ    200704           // 256*784

// ws layout (float offsets)
#define OFF_CURP  0              // curp [13][256][400]   (sc1)
#define OFF_SPPO  1331200        // (spk,post) [256][832] (sc1)
#define OFF_FLAGS 1544192        // u32 flags[256]        (sc1)
#define OFF_BAR   1544448        // u32 bar[4096]
#define WS_FLOATS 1548544

typedef unsigned long long ull;

// ---- agent-coherent (sc1) access helpers ----
__device__ __forceinline__ float ld_coh(const float* p) {
  return __hip_atomic_load(p, __ATOMIC_RELAXED, __HIP_MEMORY_SCOPE_AGENT);
}
__device__ __forceinline__ void st_coh(float* p, float v) {
  __hip_atomic_store(p, v, __ATOMIC_RELAXED, __HIP_MEMORY_SCOPE_AGENT);
}
__device__ __forceinline__ void st_coh2(float* p, float2 v) {
  union { ull u; float2 f; } c; c.f = v;
  __hip_atomic_store((ull*)p, c.u, __ATOMIC_RELAXED, __HIP_MEMORY_SCOPE_AGENT);
}

__device__ __forceinline__ void gl_lds16(const float* g, float* l) {       // cached
  __builtin_amdgcn_global_load_lds(
      (const __attribute__((address_space(1))) void*)g,
      (__attribute__((address_space(3))) void*)l, 16, 0, 0);
}
__device__ __forceinline__ void gl_lds16c(const float* g, float* l) {      // sc1
  __builtin_amdgcn_global_load_lds(
      (const __attribute__((address_space(1))) void*)g,
      (__attribute__((address_space(3))) void*)l, 16, 0, 0x10);
}

// Hierarchical fence-free grid barrier (32 groups x 8), monotonic counters.
__device__ __forceinline__ void gbar(unsigned* bar, unsigned k, int blk) {
  __syncthreads();
  if (threadIdx.x == 0) {
    const int g = blk >> 3;
    unsigned* garr = bar + g * 64;
    unsigned* ggen = bar + g * 64 + 32;
    unsigned* rarr = bar + 32 * 64;
    unsigned* rgen = bar + 32 * 64 + 32;
    unsigned a = __hip_atomic_fetch_add(garr, 1u, __ATOMIC_RELAXED,
                                        __HIP_MEMORY_SCOPE_AGENT);
    if (a + 1u == k * 8u) {
      unsigned r = __hip_atomic_fetch_add(rarr, 1u, __ATOMIC_RELAXED,
                                          __HIP_MEMORY_SCOPE_AGENT);
      if (r + 1u == k * 32u) {
        __hip_atomic_store(rgen, k, __ATOMIC_RELAXED, __HIP_MEMORY_SCOPE_AGENT);
      } else {
        while (__hip_atomic_load(rgen, __ATOMIC_RELAXED,
                                 __HIP_MEMORY_SCOPE_AGENT) < k)
          __builtin_amdgcn_s_sleep(1);
      }
      __hip_atomic_store(ggen, k, __ATOMIC_RELAXED, __HIP_MEMORY_SCOPE_AGENT);
    } else {
      while (__hip_atomic_load(ggen, __ATOMIC_RELAXED,
                               __HIP_MEMORY_SCOPE_AGENT) < k)
        __builtin_amdgcn_s_sleep(1);
    }
  }
  __syncthreads();
}

__device__ __forceinline__ float clip01(float x) {
  return fminf(fmaxf(x, 0.0f), 1.0f);
}

__global__ void __launch_bounds__(NTHR) snn_kernel(
    const float* __restrict__ img,   // [200][256][784]
    const float* __restrict__ Win,   // [400][784]
    float* __restrict__ out,         // mem_rec | spk_rec | W_final
    float* ws)
{
  float*    curp  = ws + OFF_CURP;
  float*    sppo  = ws + OFF_SPPO;
  unsigned* flags = (unsigned*)(ws + OFF_FLAGS);
  unsigned* bar   = (unsigned*)(ws + OFF_BAR);

  float* mem_rec = out;
  float* spk_rec = out + (size_t)T_STEPS * BATCH * NOUT;
  float* Wout    = out + (size_t)2 * T_STEPS * BATCH * NOUT;

  const int tid = threadIdx.x;
  const int blk = blockIdx.x;
  const int wv = tid >> 6, ln = tid & 63;
  unsigned bt = 0;

  // phase-2 geometry (meaningful for blk < 169)
  const int bi = blk / 13, bn = blk % 13;
  const int ib0 = bi * 64, nb0 = bn * 32;
  const int brow0 = wv * 4 + (ln >> 4);
  int icol = ib0 + (ln & 15) * 4;
  if (icol > INQ - 4) icol = INQ - 4;       // clamp (garbage, unused)
  const int scol = 2 * nb0 + (ln & 15) * 4;
  const int il = ln >> 3, nl = ln & 7;
  const int loff = il * 8;                  // tr/img lane col (8 floats)
  const int soff = nl * 8;                  // sppo lane col (4 (s,p) pairs)

  __shared__ float s_W[64][33];             // W panel, +1 pad (bank spread)
  __shared__ float tr_lds[BATCH][64];       // persistent pre-trace panel
  __shared__ float stg[2][4096];            // [buf][img 2048 | sppo 2048]
  __shared__ int   s_red8[8];
  __shared__ int   s_win;

  // persistent per-thread neuron state (thread tid = neuron n of row blk)
  float syn_r = 0.0f, mem_r = 0.0f, po_r = 0.0f;

  // scatter: curp[bi][b][nb0..] = sum over active i (ascending) of W panel
  auto scatter = [&](int tt) {
    const float* imt = img + (size_t)tt * IMSZ;
    const int b0 = wv * 32;
    for (int bb = 0; bb < 32; bb += 8) {
      float v[8];
      #pragma unroll
      for (int q = 0; q < 8; ++q) {
        const int gi = ib0 + ln;
        v[q] = imt[(size_t)(b0 + bb + q) * INQ + (gi < INQ ? gi : INQ - 1)];
      }
      #pragma unroll
      for (int q = 0; q < 8; ++q) {
        const bool act = (ib0 + ln < INQ) && (v[q] != 0.0f);
        ull m = __ballot(act);
        float acc = 0.0f;
        while (m) {                          // ascending i (ctz from LSB)
          const int i = (int)__builtin_ctzll(m);
          m &= m - 1ull;
          acc += s_W[i][ln & 31];            // lanes>=32 mirror (broadcast)
        }
        if (ln < 32 && nb0 + ln < NOUT)
          st_coh(curp + ((size_t)bi * BATCH + (b0 + bb + q)) * 400 + nb0 + ln,
                 acc);
      }
    }
  };

  // ---- prologue: load W panel, zero trace, scatter cur for t=0 ----
  if (blk < 169) {
    for (int e = tid; e < 64 * 33; e += NTHR) (&s_W[0][0])[e] = 0.0f;
    for (int e = tid; e < BATCH * 64; e += NTHR) (&tr_lds[0][0])[e] = 0.0f;
    __syncthreads();
    for (int e = tid; e < 2048; e += NTHR) {
      const int i = e >> 5, n = e & 31;
      const int gi = ib0 + i, gn = nb0 + n;
      if (gi < INQ && gn < NOUT) s_W[i][n] = Win[(size_t)gn * INQ + gi];
    }
    __syncthreads();
    scatter(0);
  }
  if (tid == 0) s_win = 0;
  ++bt; gbar(bar, bt, blk);

  for (int t = 0; t < T_STEPS; ++t) {
    const float* imgt = img + (size_t)t * IMSZ;

    // ================= phase 1: row b = blk, register state ================
    {
      const int b = blk;
      const int anyPrev = (t > 0)
          ? (int)__hip_atomic_load(&flags[t - 1], __ATOMIC_RELAXED, __HIP_MEMORY_SCOPE_AGENT)
          : 0;
      const int wPrev = s_win;
      int localmin = 0x7fffffff;

      if (tid < NOUT) {
        const int n = tid;
        float p[13];
        #pragma unroll
        for (int q = 0; q < 13; ++q)
          p[q] = ld_coh(curp + ((size_t)q * BATCH + b) * 400 + n);
        float c0 = 0.0f;
        #pragma unroll
        for (int q = 0; q < 13; ++q) c0 += p[q];   // ascending i-panels
        float sv = syn_r;
        if (anyPrev && n != wPrev) sv -= 0.1f;
        const float syn0 = fmaf(0.9f, sv, c0);
        const float r0 = (mem_r > 1.0f) ? 1.0f : 0.0f;
        const float m0 = fmaf(0.8f, mem_r, syn0) - r0;
        const float s0 = (m0 > 1.0f) ? 1.0f : 0.0f;
        syn_r = syn0; mem_r = m0;
        po_r = fmaf(0.9f, po_r, s0);
        st_coh2(sppo + (size_t)b * 832 + 2 * n, make_float2(s0, po_r));
        const size_t ridx = (size_t)t * BATCH * NOUT + (size_t)b * NOUT + n;
        mem_rec[ridx] = m0;
        spk_rec[ridx] = s0;
        if (s0 != 0.0f) localmin = n;
      }
      int v = localmin;
      #pragma unroll
      for (int s = 1; s < 64; s <<= 1) v = min(v, __shfl_xor(v, s));
      if (ln == 0) s_red8[wv] = v;
      __syncthreads();
      if (tid == 0) {
        int w = s_red8[0];
        #pragma unroll
        for (int q = 1; q < 8; ++q) w = min(w, s_red8[q]);
        s_win = (w == 0x7fffffff) ? 0 : w;
        if (w != 0x7fffffff)
          __hip_atomic_fetch_or(&flags[t], 1u, __ATOMIC_RELAXED, __HIP_MEMORY_SCOPE_AGENT);
      }
    }
    ++bt; gbar(bar, bt, blk);

    // ================= phase 2: STDP into LDS panel + scatter ==============
    if (blk < 169) {
      float a[8][4] = {};                   // (8i,4n) partial over b≡wv mod 8

      #define STG(c, buf) {                                                    \
        int br_ = (c) * 32 + brow0;                                            \
        gl_lds16 (imgt + (size_t)br_ * INQ + icol, &stg[buf][wv * 256]);       \
        gl_lds16c(sppo + (size_t)br_ * 832 + scol,                             \
                  &stg[buf][2048 + wv * 256]);                                 \
      }

      STG(0, 0);
      for (int c = 0; c < 8; ++c) {
        const int buf = c & 1;
        if (c < 7) {
          STG(c + 1, buf ^ 1);
          __builtin_amdgcn_s_waitcnt(0x0F72);   // vmcnt(2): chunk c landed
        } else {
          __builtin_amdgcn_s_waitcnt(0x0F70);   // vmcnt(0)
        }
        __builtin_amdgcn_s_barrier();
        #pragma unroll
        for (int k = 0; k < 4; ++k) {
          const int r = 8 * k + wv;             // this wave's rows (exclusive)
          const int gb = c * 32 + r;
          const float4 tA = *(const float4*)&tr_lds[gb][loff];
          const float4 tB = *(const float4*)&tr_lds[gb][loff + 4];
          const float4 gA = *(const float4*)&stg[buf][r * 64 + loff];
          const float4 gB = *(const float4*)&stg[buf][r * 64 + loff + 4];
          const float4 sA = *(const float4*)&stg[buf][2048 + r * 64 + soff];
          const float4 sB = *(const float4*)&stg[buf][2048 + r * 64 + soff + 4];
          const float tv[8] = { tA.x, tA.y, tA.z, tA.w, tB.x, tB.y, tB.z, tB.w };
          const float gv[8] = { gA.x, gA.y, gA.z, gA.w, gB.x, gB.y, gB.z, gB.w };
          const float ap[4] = { 1e-3f * sA.x, 1e-3f * sA.z, 1e-3f * sB.x, 1e-3f * sB.z };
          const float am[4] = { 1e-3f * sA.y, 1e-3f * sA.w, 1e-3f * sB.y, 1e-3f * sB.w };
          #pragma unroll
          for (int ii = 0; ii < 8; ++ii)
            #pragma unroll
            for (int nn = 0; nn < 4; ++nn)
              a[ii][nn] = fmaf(tv[ii], ap[nn], fmaf(gv[ii], -am[nn], a[ii][nn]));
          // inline trace recurrence (row gb is exclusive to this wave):
          // tr[t+1] = 0.9*tr[t] + img[t]; nl==0 lanes cover all 64 cols
          if (nl == 0) {
            *(float4*)&tr_lds[gb][loff] = make_float4(
                fmaf(0.9f, tA.x, gA.x), fmaf(0.9f, tA.y, gA.y),
                fmaf(0.9f, tA.z, gA.z), fmaf(0.9f, tA.w, gA.w));
            *(float4*)&tr_lds[gb][loff + 4] = make_float4(
                fmaf(0.9f, tB.x, gB.x), fmaf(0.9f, tB.y, gB.y),
                fmaf(0.9f, tB.z, gB.z), fmaf(0.9f, tB.w, gB.w));
          }
        }
        __builtin_amdgcn_s_waitcnt(0xC07F);     // lgkmcnt(0) only
        __builtin_amdgcn_s_barrier();
      }
      #undef STG

      // ---- combine 8 wave partials (two fixed-order 4-wave rounds) ----
      float* part = &stg[0][0];                 // [4][32][64] floats
      const int kbase = wv * 4;
      const int lcol  = ln;
      float dsum[4];

      if (wv < 4) {
        #pragma unroll
        for (int ii = 0; ii < 8; ++ii)
          #pragma unroll
          for (int nn = 0; nn < 4; ++nn)
            part[(wv * 32 + (ii * 4 + nn)) * 64 + ln] = a[ii][nn];
      }
      __syncthreads();
      #pragma unroll
      for (int kk = 0; kk < 4; ++kk) {
        const int k = kbase + kk;
        dsum[kk] = ((part[k * 64 + lcol] + part[2048 + k * 64 + lcol])
                    + part[4096 + k * 64 + lcol]) + part[6144 + k * 64 + lcol];
      }
      __syncthreads();
      if (wv >= 4) {
        #pragma unroll
        for (int ii = 0; ii < 8; ++ii)
          #pragma unroll
          for (int nn = 0; nn < 4; ++nn)
            part[((wv - 4) * 32 + (ii * 4 + nn)) * 64 + ln] = a[ii][nn];
      }
      __syncthreads();
      #pragma unroll
      for (int kk = 0; kk < 4; ++kk) {
        const int k = kbase + kk;
        dsum[kk] += ((part[k * 64 + lcol] + part[2048 + k * 64 + lcol])
                     + part[4096 + k * 64 + lcol]) + part[6144 + k * 64 + lcol];
      }

      // ---- W RMW in LDS: thread = (1 i, 4 n) ----
      {
        const int i_loc = (lcol >> 3) * 8 + wv;
        const int n_loc = (lcol & 7) * 4;
        float* wp = &s_W[i_loc][n_loc];
        #pragma unroll
        for (int q = 0; q < 4; ++q)
          wp[q] = clip01(wp[q] + dsum[q]);
      }
      __syncthreads();                          // panel updated for scatter

      if (t + 1 < T_STEPS) scatter(t + 1);
    }
    ++bt; gbar(bar, bt, blk);
  }

  // ---- epilogue: W_final from LDS panels ----
  if (blk < 169) {
    for (int e = tid; e < 2048; e += NTHR) {
      const int i = e >> 5, n = e & 31;
      const int gi = ib0 + i, gn = nb0 + n;
      if (gi < INQ && gn < NOUT)
        Wout[(size_t)gn * INQ + gi] = s_W[i][n];
    }
  }
}

extern "C" void kernel_launch(void* const* d_in, const int* in_sizes, int n_in,
                              void* d_out, int out_size, void* d_ws, size_t ws_size,
                              hipStream_t stream) {
  const float* img = (const float*)d_in[0];
  const float* W   = (const float*)d_in[1];
  float* out = (float*)d_out;
  float* ws  = (float*)d_ws;

  hipMemsetAsync(d_ws, 0, (size_t)WS_FLOATS * sizeof(float), stream);

  void* args[] = { (void*)&img, (void*)&W, (void*)&out, (void*)&ws };
  hipLaunchCooperativeKernel((const void*)snn_kernel, dim3(GRID), dim3(NTHR),
                             args, 0, stream);
}

// Round 9
// 4620.748 us; speedup vs baseline: 1.8229x; 1.8229x over previous
//
#include <hip/hip_runtime.h>

// SNN-MNIST forward + STDP, MI355X persistent cooperative kernel.
// Round 13: R9 base (5000 us, verified) with ONE phase-2 change: each wave
// now computes exactly the 4 rows it stages (own LDS slot) instead of rows
// r==wv (mod 8) staged by other waves. This removes ALL 16 per-chunk
// s_barriers per step (waves fully decoupled in the chunk loop; per-wave
// vmcnt ordering suffices) and allows 2-chunk-deep prefetch (3 buffers,
// counted vmcnt(6), never drained mid-loop). b-sum becomes a different
// fixed regrouping (tolerated class). Phase 1 / combine / RMW / trace
// epoch / list build / grid barriers: R9 verbatim. R12's panel-resident W
// rejected (serial scatter + 1.3e7 bank conflicts, 8423 us).

#define T_STEPS 200
#define BATCH   256
#define INQ     784
#define NOUT    400
#define NP      512
#define GRID    256
#define NTHR    512
#define IMSZ    200704           // 256*784

// ws layout (float offsets) — R9 verbatim
#define OFF_WT    0            // Wt [785][512] (row 784 = zero pad for gather)
#define OFF_SYN   401920       // syn [256][512]         (block-private)
#define OFF_MEM   532992       // mem [256][512]         (block-private)
#define OFF_SPPO  664064       // interleaved (spk,post): [256][1024]  (sc1)
#define OFF_TRA   926208       // trA [256][784]         (sc1)
#define OFF_TRB   1126912      // trB [256][784]         (sc1)
#define OFF_WIN   1327616      // int win[256]           (block-private)
#define OFF_FLAGS 1327872      // int flags[256]         (sc1)
#define OFF_BAR   1328128      // unsigned bar[4096]: hierarchical barrier
#define WS_FLOATS 1332224

typedef unsigned long long ull;

// ---- agent-coherent (sc1) access helpers ----
__device__ __forceinline__ float ld_coh(const float* p) {
  return __hip_atomic_load(p, __ATOMIC_RELAXED, __HIP_MEMORY_SCOPE_AGENT);
}
__device__ __forceinline__ float2 ld_coh2(const float* p) {
  union { ull u; float2 f; } c;
  c.u = __hip_atomic_load((const ull*)p, __ATOMIC_RELAXED, __HIP_MEMORY_SCOPE_AGENT);
  return c.f;
}
__device__ __forceinline__ void st_coh(float* p, float v) {
  __hip_atomic_store(p, v, __ATOMIC_RELAXED, __HIP_MEMORY_SCOPE_AGENT);
}
__device__ __forceinline__ void st_coh2(float* p, float2 v) {
  union { ull u; float2 f; } c; c.f = v;
  __hip_atomic_store((ull*)p, c.u, __ATOMIC_RELAXED, __HIP_MEMORY_SCOPE_AGENT);
}

__device__ __forceinline__ void gl_lds16(const float* g, float* l) {       // cached
  __builtin_amdgcn_global_load_lds(
      (const __attribute__((address_space(1))) void*)g,
      (__attribute__((address_space(3))) void*)l, 16, 0, 0);
}
__device__ __forceinline__ void gl_lds16c(const float* g, float* l) {      // sc1
  __builtin_amdgcn_global_load_lds(
      (const __attribute__((address_space(1))) void*)g,
      (__attribute__((address_space(3))) void*)l, 16, 0, 0x10);
}

// Hierarchical fence-free grid barrier (32 groups x 8), monotonic counters.
__device__ __forceinline__ void gbar(unsigned* bar, unsigned k, int blk) {
  __syncthreads();
  if (threadIdx.x == 0) {
    const int g = blk >> 3;
    unsigned* garr = bar + g * 64;
    unsigned* ggen = bar + g * 64 + 32;
    unsigned* rarr = bar + 32 * 64;
    unsigned* rgen = bar + 32 * 64 + 32;
    unsigned a = __hip_atomic_fetch_add(garr, 1u, __ATOMIC_RELAXED,
                                        __HIP_MEMORY_SCOPE_AGENT);
    if (a + 1u == k * 8u) {
      unsigned r = __hip_atomic_fetch_add(rarr, 1u, __ATOMIC_RELAXED,
                                          __HIP_MEMORY_SCOPE_AGENT);
      if (r + 1u == k * 32u) {
        __hip_atomic_store(rgen, k, __ATOMIC_RELAXED, __HIP_MEMORY_SCOPE_AGENT);
      } else {
        while (__hip_atomic_load(rgen, __ATOMIC_RELAXED,
                                 __HIP_MEMORY_SCOPE_AGENT) < k)
          __builtin_amdgcn_s_sleep(1);
      }
      __hip_atomic_store(ggen, k, __ATOMIC_RELAXED, __HIP_MEMORY_SCOPE_AGENT);
    } else {
      while (__hip_atomic_load(ggen, __ATOMIC_RELAXED,
                               __HIP_MEMORY_SCOPE_AGENT) < k)
        __builtin_amdgcn_s_sleep(1);
    }
  }
  __syncthreads();
}

__device__ __forceinline__ float clip01(float x) {
  return fminf(fmaxf(x, 0.0f), 1.0f);
}

__global__ void __launch_bounds__(NTHR) snn_kernel(
    const float* __restrict__ img,   // [200][256][784]
    const float* __restrict__ Win,   // [400][784]
    float* __restrict__ out,         // mem_rec | spk_rec | W_final
    float* ws)
{
  float* Wt    = ws + OFF_WT;
  float* syn   = ws + OFF_SYN;
  float* mem   = ws + OFF_MEM;
  float* sppo  = ws + OFF_SPPO;
  float* trA   = ws + OFF_TRA;
  float* trB   = ws + OFF_TRB;
  int*   win   = (int*)(ws + OFF_WIN);
  unsigned* flags = (unsigned*)(ws + OFF_FLAGS);
  unsigned* bar   = (unsigned*)(ws + OFF_BAR);

  float* mem_rec = out;
  float* spk_rec = out + (size_t)T_STEPS * BATCH * NOUT;
  float* Wout    = out + (size_t)2 * T_STEPS * BATCH * NOUT;

  const int tid = threadIdx.x;
  const int blk = blockIdx.x;
  const int wv = tid >> 6, ln = tid & 63;
  unsigned bt = 0;

  __shared__ int   s_list[2][800];
  __shared__ int   s_cnt2[2];
  __shared__ ull   s_msk[13];
  __shared__ int   s_pref[14];
  __shared__ int   s_red8[8];
  __shared__ float stg[3][6144];      // [buf][tr 2048 | img 2048 | sppo 2048]

  // Parallel ordered active-index compaction for img[tt] row blk -> s_list[slot].
  auto build_list = [&](int tt, int slot) {
    const float* row = img + (size_t)tt * IMSZ + (size_t)blk * INQ;
    for (int c = wv; c < 13; c += 8) {
      int i = c * 64 + ln;
      bool act = (i < INQ) && (row[i] != 0.0f);
      ull m = __ballot(act);
      if (ln == 0) s_msk[c] = m;
    }
    __syncthreads();
    if (tid == 0) {
      int acc = 0;
      for (int c = 0; c < 13; ++c) { s_pref[c] = acc; acc += (int)__popcll(s_msk[c]); }
      s_pref[13] = acc;
      s_cnt2[slot] = (acc + 15) & ~15;
    }
    __syncthreads();
    for (int c = wv; c < 13; c += 8) {
      ull m = s_msk[c];
      if ((m >> ln) & 1ull)
        s_list[slot][s_pref[c] + (int)__popcll(m & ((1ull << ln) - 1ull))] =
            c * 64 + ln;
    }
    int base = s_pref[13];
    int cr = (base + 15) & ~15;
    if (tid < cr - base) s_list[slot][base + tid] = 784;   // zero-row sentinel
  };

  // ---- prologue: Wt[i][n] = Win[n][i]; list(0) ----
  for (int e = blk * NTHR + tid; e < NOUT * INQ; e += GRID * NTHR) {
    int n = e / INQ, i = e % INQ;
    st_coh(Wt + (size_t)i * NP + n, Win[e]);
  }
  build_list(0, 0);
  ++bt; gbar(bar, bt, blk);

  for (int t = 0; t < T_STEPS; ++t) {
    float* trC = (t & 1) ? trB : trA;   // pre_traces[t]
    float* trN = (t & 1) ? trA : trB;   // pre_traces[t+1]

    // ================= phase 1: block b = batch row (gather + state) ========
    {
      const int b = blk;
      const int slot = t & 1;
      const int cnt = s_cnt2[slot];
      const int anyPrev = (t > 0)
          ? (int)__hip_atomic_load(&flags[t - 1], __ATOMIC_RELAXED, __HIP_MEMORY_SCOPE_AGENT)
          : 0;
      const int wPrev = win[b];
      int localmin = 0x7fffffff;

      if (tid < NOUT) {
        const int n = tid;                 // 1 neuron per thread
        const size_t sidx = (size_t)b * NP + n;
        // hoisted sppo load (latency hidden under gather)
        float2 sp = ld_coh2(sppo + (size_t)b * 1024 + 2 * n);
        float sv = syn[sidx];
        if (anyPrev && n != wPrev) sv -= 0.1f;
        float c0 = 0.f;
        const int* lrow = s_list[slot];
        for (int j = 0; j < cnt; j += 16) {   // 16 coherent scalar loads in flight
          float q0  = ld_coh(Wt + (size_t)lrow[j+0]  * NP + n);
          float q1  = ld_coh(Wt + (size_t)lrow[j+1]  * NP + n);
          float q2  = ld_coh(Wt + (size_t)lrow[j+2]  * NP + n);
          float q3  = ld_coh(Wt + (size_t)lrow[j+3]  * NP + n);
          float q4  = ld_coh(Wt + (size_t)lrow[j+4]  * NP + n);
          float q5  = ld_coh(Wt + (size_t)lrow[j+5]  * NP + n);
          float q6  = ld_coh(Wt + (size_t)lrow[j+6]  * NP + n);
          float q7  = ld_coh(Wt + (size_t)lrow[j+7]  * NP + n);
          float q8  = ld_coh(Wt + (size_t)lrow[j+8]  * NP + n);
          float q9  = ld_coh(Wt + (size_t)lrow[j+9]  * NP + n);
          float q10 = ld_coh(Wt + (size_t)lrow[j+10] * NP + n);
          float q11 = ld_coh(Wt + (size_t)lrow[j+11] * NP + n);
          float q12 = ld_coh(Wt + (size_t)lrow[j+12] * NP + n);
          float q13 = ld_coh(Wt + (size_t)lrow[j+13] * NP + n);
          float q14 = ld_coh(Wt + (size_t)lrow[j+14] * NP + n);
          float q15 = ld_coh(Wt + (size_t)lrow[j+15] * NP + n);
          c0 += q0;  c0 += q1;  c0 += q2;  c0 += q3;
          c0 += q4;  c0 += q5;  c0 += q6;  c0 += q7;
          c0 += q8;  c0 += q9;  c0 += q10; c0 += q11;
          c0 += q12; c0 += q13; c0 += q14; c0 += q15;
        }
        float mv = mem[sidx];
        float syn0 = fmaf(0.9f, sv, c0);
        float r0 = (mv > 1.0f) ? 1.0f : 0.0f;
        float m0 = fmaf(0.8f, mv, syn0) - r0;
        float s0 = (m0 > 1.0f) ? 1.0f : 0.0f;
        syn[sidx] = syn0;
        mem[sidx] = m0;
        float p0 = fmaf(0.9f, sp.y, s0);
        st_coh2(sppo + (size_t)b * 1024 + 2 * n, make_float2(s0, p0));
        const size_t ridx = (size_t)t * BATCH * NOUT + (size_t)b * NOUT + n;
        mem_rec[ridx] = m0;
        spk_rec[ridx] = s0;
        if (s0 != 0.f) localmin = n;
      }
      int v = localmin;
      #pragma unroll
      for (int s = 1; s < 64; s <<= 1) v = min(v, __shfl_xor(v, s));
      if (ln == 0) s_red8[wv] = v;
      __syncthreads();
      if (tid == 0) {
        int w = s_red8[0];
        #pragma unroll
        for (int q = 1; q < 8; ++q) w = min(w, s_red8[q]);
        win[b] = (w == 0x7fffffff) ? 0 : w;
        if (w != 0x7fffffff)
          __hip_atomic_fetch_or(&flags[t], 1u, __ATOMIC_RELAXED, __HIP_MEMORY_SCOPE_AGENT);
      }
    }
    ++bt; gbar(bar, bt, blk);

    // ================= phase 2: STDP weight update (LDS-staged) =============
    // 169 blocks = 13 i-blocks (64 i) x 13 n-blocks (32 n). 8 waves; wave w
    // stages AND computes rows c*32 + w*4 .. +3 (its own LDS slot) -> no
    // intra-loop barriers; 2-chunk-deep prefetch with counted vmcnt.
    if (blk < 169) {
      const int bi = blk / 13, bn = blk % 13;
      const int ib0 = bi * 64, nb0 = bn * 32;
      const int brow0 = wv * 4 + (ln >> 4);
      int icol = ib0 + (ln & 15) * 4;
      if (icol > INQ - 4) icol = INQ - 4;         // clamp (garbage, unused)
      const int scol = 2 * nb0 + (ln & 15) * 4;
      const float* imgt = img + (size_t)t * BATCH * INQ;

      const int il = ln >> 3, nl = ln & 7;
      const int loff = il * 8;                    // tr/img lane col (8 floats)
      const int soff = nl * 8;                    // sppo lane col (4 (s,p) pairs)
      const int wb = wv * 256;                    // wave slot base (floats)

      float a[8][4] = {};                         // (8i,4n), b = c*32+wv*4+q

      // stage chunk c rows wv*4..wv*4+3 into OWN slot: tr/sppo sc1, img cached
      #define STG(c, buf) {                                                     \
        int br = (c) * 32 + brow0;                                              \
        float* dst = &stg[buf][wb];                                             \
        gl_lds16c(trC  + (size_t)br * INQ  + icol, dst);                        \
        gl_lds16 (imgt + (size_t)br * INQ  + icol, dst + 2048);                 \
        gl_lds16c(sppo + (size_t)br * 1024 + scol, dst + 4096);                 \
      }

      STG(0, 0);
      STG(1, 1);
      for (int c = 0; c < 8; ++c) {
        const int buf = c % 3;
        if (c + 2 < 8) {
          STG(c + 2, (c + 2) % 3);
          __builtin_amdgcn_s_waitcnt(0x0F76);     // vmcnt(6): chunk c landed
        } else if (c == 6) {
          __builtin_amdgcn_s_waitcnt(0x0F73);     // vmcnt(3)
        } else {
          __builtin_amdgcn_s_waitcnt(0x0F70);     // vmcnt(0)
        }
        #pragma unroll
        for (int q = 0; q < 4; ++q) {             // own rows, ascending b
          const int rb = wb + q * 64;
          const float4 tA = *(const float4*)&stg[buf][rb + loff];
          const float4 tB = *(const float4*)&stg[buf][rb + loff + 4];
          const float4 gA = *(const float4*)&stg[buf][2048 + rb + loff];
          const float4 gB = *(const float4*)&stg[buf][2048 + rb + loff + 4];
          const float4 sA = *(const float4*)&stg[buf][4096 + rb + soff];
          const float4 sB = *(const float4*)&stg[buf][4096 + rb + soff + 4];
          const float tv[8] = { tA.x, tA.y, tA.z, tA.w, tB.x, tB.y, tB.z, tB.w };
          const float gv[8] = { gA.x, gA.y, gA.z, gA.w, gB.x, gB.y, gB.z, gB.w };
          const float ap[4] = { 1e-3f * sA.x, 1e-3f * sA.z, 1e-3f * sB.x, 1e-3f * sB.z };
          const float am[4] = { 1e-3f * sA.y, 1e-3f * sA.w, 1e-3f * sB.y, 1e-3f * sB.w };
          #pragma unroll
          for (int ii = 0; ii < 8; ++ii)
            #pragma unroll
            for (int nn = 0; nn < 4; ++nn)
              a[ii][nn] = fmaf(tv[ii], ap[nn], fmaf(gv[ii], -am[nn], a[ii][nn]));
        }
      }
      #undef STG
      __syncthreads();                            // all waves done with stg

      // ---- combine 8 wave partials in two fixed-order 4-wave rounds ----
      // part[w'][k][l], k = ii*4+nn; [4][32][64] floats = 8192 (fits in stg).
      float* part = &stg[0][0];
      const int kbase = (tid >> 6) * 4;           // this thread's 4 k-slots
      const int lcol  = tid & 63;
      float dsum[4];

      if (wv < 4) {
        #pragma unroll
        for (int ii = 0; ii < 8; ++ii)
          #pragma unroll
          for (int nn = 0; nn < 4; ++nn)
            part[(wv * 32 + (ii * 4 + nn)) * 64 + ln] = a[ii][nn];
      }
      __syncthreads();
      #pragma unroll
      for (int kk = 0; kk < 4; ++kk) {
        const int k = kbase + kk;
        dsum[kk] = ((part[k * 64 + lcol] + part[2048 + k * 64 + lcol])
                    + part[4096 + k * 64 + lcol]) + part[6144 + k * 64 + lcol];
      }
      __syncthreads();
      if (wv >= 4) {
        #pragma unroll
        for (int ii = 0; ii < 8; ++ii)
          #pragma unroll
          for (int nn = 0; nn < 4; ++nn)
            part[((wv - 4) * 32 + (ii * 4 + nn)) * 64 + ln] = a[ii][nn];
      }
      __syncthreads();
      #pragma unroll
      for (int kk = 0; kk < 4; ++kk) {
        const int k = kbase + kk;
        dsum[kk] += ((part[k * 64 + lcol] + part[2048 + k * 64 + lcol])
                     + part[4096 + k * 64 + lcol]) + part[6144 + k * 64 + lcol];
      }

      // ---- coherent Wt RMW: 1 i x 4 n per thread ----
      const int iO = ib0 + (lcol >> 3) * 8 + (tid >> 6);
      const int nO = nb0 + (lcol & 7) * 4;
      if (nO < NOUT && iO < INQ) {
        float* wp = Wt + (size_t)iO * NP + nO;
        float2 w2 = ld_coh2(wp);
        w2.x = clip01(w2.x + dsum[0]);
        w2.y = clip01(w2.y + dsum[1]);
        st_coh2(wp, w2);
        float2 w3 = ld_coh2(wp + 2);
        w3.x = clip01(w3.x + dsum[2]);
        w3.y = clip01(w3.y + dsum[3]);
        st_coh2(wp + 2, w3);
      }
    }

    // ---- all blocks: trace recurrence + next list (own row), in P2 epoch ---
    {
      const float* imrow = img + (size_t)t * IMSZ + (size_t)blk * INQ;
      const float* trCrow = trC + (size_t)blk * INQ;
      float* trNrow = trN + (size_t)blk * INQ;
      for (int i = tid * 2; i < INQ; i += 2 * NTHR) {
        float2 o = ld_coh2(trCrow + i);
        float2 iv = *(const float2*)(imrow + i);
        st_coh2(trNrow + i, make_float2(fmaf(0.9f, o.x, iv.x),
                                        fmaf(0.9f, o.y, iv.y)));
      }
    }
    if (t + 1 < T_STEPS) build_list(t + 1, (t + 1) & 1);

    ++bt; gbar(bar, bt, blk);
  }

  // ---- final: W_out[n][i] = Wt[i][n] ----
  for (int e = blk * NTHR + tid; e < NOUT * INQ; e += GRID * NTHR) {
    int n = e / INQ, i = e % INQ;
    Wout[e] = ld_coh(Wt + (size_t)i * NP + n);
  }
}

extern "C" void kernel_launch(void* const* d_in, const int* in_sizes, int n_in,
                              void* d_out, int out_size, void* d_ws, size_t ws_size,
                              hipStream_t stream) {
  const float* img = (const float*)d_in[0];
  const float* W   = (const float*)d_in[1];
  float* out = (float*)d_out;
  float* ws  = (float*)d_ws;

  hipMemsetAsync(d_ws, 0, (size_t)WS_FLOATS * sizeof(float), stream);

  void* args[] = { (void*)&img, (void*)&W, (void*)&out, (void*)&ws };
  hipLaunchCooperativeKernel((const void*)snn_kernel, dim3(GRID), dim3(NTHR),
                             args, 0, stream);
}